// Round 4
// baseline (31468.613 us; speedup 1.0000x reference)
//
#include <hip/hip_runtime.h>
#include <stdint.h>

#define T_STEPS 4096
#define BATCH 32
#define HID 512
#define GROUPS 8            // blocks per batch
#define BLK_THREADS 1024    // 16 waves; 256 blocks = exactly 1/CU
#define NBLOCKS 256
#define BSLOT_DW 256                 // dwords per (slot,batch) h record: 8 groups x 32
#define SLOT_DW (BATCH * BSLOT_DW)   // dwords per parity slot (8192 = 32 KB)

typedef _Float16 h2_t __attribute__((ext_vector_type(2)));
typedef uint32_t u32x4 __attribute__((ext_vector_type(4)));
typedef uint32_t u32x8 __attribute__((ext_vector_type(8)));

__device__ inline uint32_t pack_h2(float a, float b) {
  h2_t v;
  v.x = (_Float16)a;
  v.y = (_Float16)b;
  return __builtin_bit_cast(uint32_t, v);
}

__device__ inline float fdot2(uint32_t a, uint32_t b, float c) {
  return __builtin_amdgcn_fdot2(__builtin_bit_cast(h2_t, a),
                                __builtin_bit_cast(h2_t, b), c, false);
}

// Launder a wave-uniform pointer into an SGPR-resident uint64 for "s" asm.
__device__ inline uint64_t uni64(const void* p) {
  uint32_t lo = __builtin_amdgcn_readfirstlane((uint32_t)(uintptr_t)p);
  uint32_t hi = __builtin_amdgcn_readfirstlane((uint32_t)((uintptr_t)p >> 32));
  return ((uint64_t)hi << 32) | lo;
}

// Scalar K$ invalidate: next s_load misses K$ -> fresh from the XCD's L2
// (same-XCD guaranteed by the claim protocol). ONLY WAVE 15 runs this now:
// round-11 showed 16 waves x {inv + 8 s_loads} through one scalar unit /
// small-MSHR K$ was the poll storm; round-12 showed agent-scope (sc1)
// atomics are far worse (MALL-level RTs, WRITE_SIZE 33->217 MB).
__device__ inline void kinv() {
  asm volatile("s_dcache_inv" ::: "memory");
}
__device__ inline u32x8 sload8(uint64_t p) {
  u32x8 v;
  asm volatile("s_load_dwordx8 %0, %1, 0x0\n\ts_waitcnt lgkmcnt(0)"
               : "=&s"(v) : "s"(p) : "memory");
  return v;
}

__device__ inline float sigf(float x) { return 1.0f / (1.0f + __expf(-x)); }
__device__ inline float tanh_fast(float x) {
  float a = fabsf(x);
  float e = __expf(-2.0f * a);
  float r = (1.0f - e) / (1.0f + e);
  return copysignf(r, x);
}

// Round 13: single-poller, hybrid transport (all traffic stays in the XCD L2).
//   producer (wave 0): 64 plain 2B h-stores (write-through vL1 -> L2) ->
//                      s_waitcnt vmcnt(0) -> plain volatile tag store.
//   poller  (wave 15): scalar poll {s_dcache_inv; s_load_dwordx8 tags} until
//                      all 8 >= t; then fence(acquire, agent) — on gfx950
//                      this lowers to s_waitcnt + buffer_inv (vL1 invalidate
//                      for this CU, shared by all 16 waves) — then PLAIN
//                      global_load_dwordx4/lane (hits fresh L2, no sc1) of
//                      the whole 1 KB batch record -> LDS.
//   other 15 waves:    wait at barrier #1, read h via broadcast ds_read_b128.
// Tags monotonic (poll >= t), data slots parity-buffered; overwrite safety
// unchanged from rounds 9-12 (publish t+2 requires passing the t+1 barrier,
// which transitively requires all consumers to have consumed slot[t&1]).
__global__ __launch_bounds__(BLK_THREADS)
void lstm_spoll(const float* __restrict__ x0,
                const float* __restrict__ W_ih,
                const float* __restrict__ W_hh,
                const float* __restrict__ b_ih,
                const float* __restrict__ b_hh,
                const float* __restrict__ W_lin,
                const float* __restrict__ b_lin,
                float* __restrict__ y,
                uint32_t* __restrict__ h_ex,   // [2][BATCH][GROUPS][32]
                uint32_t* __restrict__ tags,   // [BATCH][8] monotonic
                int* __restrict__ claim)       // [8][16] per-XCD claim
{
  __shared__ float x0_lds[T_STEPS];     // 16 KB: this batch's x0 column
  __shared__ float ylds[T_STEPS];       // 16 KB: per-block y partials
  __shared__ float gacc[2][256];        // parity-buffered gate accumulators
  __shared__ __align__(16) uint32_t h_lds[2][BSLOT_DW];  // 2 KB: h broadcast
  __shared__ int s_bg;

  const int tid = threadIdx.x;

  // ---- claim a (batch, group) slot on THIS block's physical XCD ----
  if (tid == 0) {
    uint32_t xcc;
    asm volatile("s_getreg_b32 %0, hwreg(HW_REG_XCC_ID)" : "=s"(xcc));
    xcc &= 7;
    int slot = atomicAdd(claim + xcc * 16, 1);   // device-scope, one-time
    s_bg = (slot < 32) ? (int)(((4 * xcc + (slot >> 3)) << 3) | (slot & 7))
                       : -1;
  }
  __syncthreads();
  if (s_bg < 0) return;                  // surplus block
  const int b  = s_bg >> 3;              // batch (same XCD for all 8 groups)
  const int g  = s_bg & 7;               // group within batch
  const int u0 = g * 64;                 // first hidden unit owned
  const int wv = tid >> 6;               // wave 0..15
  const int rg = wv >> 3;                // row-group 0..1
  const int cs = wv & 7;                 // col-slice 0..7 == producer group
  const int l  = tid & 63;

  // ---- one-time: W_hh slice -> packed f16x2 -> VGPRs ----
  uint32_t w0[32], w1[32];
  {
    const int r0 = 128 * rg + l;
    const int r1 = r0 + 64;
    const int R0 = (r0 >> 6) * HID + u0 + (r0 & 63);  // gate*512 + unit
    const int R1 = (r1 >> 6) * HID + u0 + (r1 & 63);
    const float2* p0 = (const float2*)(W_hh + (size_t)R0 * HID + 64 * cs);
    const float2* p1 = (const float2*)(W_hh + (size_t)R1 * HID + 64 * cs);
#pragma unroll
    for (int k = 0; k < 32; ++k) {
      float2 a = p0[k], c = p1[k];
      w0[k] = pack_h2(a.x, a.y);
      w1[k] = pack_h2(c.x, c.y);
    }
  }
  // ---- one-time: x0 column, y partials, gacc ----
  for (int i = tid; i < T_STEPS; i += BLK_THREADS) {
    x0_lds[i] = x0[i * BATCH + b];
    ylds[i] = 0.f;
  }
  if (tid < 256) { gacc[0][tid] = 0.f; gacc[1][tid] = 0.f; }

  // ---- activation-lane constants (lanes 0..63 of wave 0) ----
  float c_state = 0.f;
  float wih_[4] = {0.f, 0.f, 0.f, 0.f}, bs_[4] = {0.f, 0.f, 0.f, 0.f};
  float wlin_u = 0.f, blin = 0.f;
  if (tid < 64) {
#pragma unroll
    for (int j = 0; j < 4; ++j) {
      int R = j * HID + u0 + tid;
      wih_[j] = W_ih[R];
      bs_[j] = b_ih[R] + b_hh[R];
    }
    wlin_u = W_lin[u0 + tid];
    blin = b_lin[0];
  }

  // ---- pointers ----
  uint32_t* tags_b = tags + b * 8;
  const uint64_t tagu = uni64(tags_b);               // scalar poll address
  uint32_t* hrec[2] = { h_ex + (size_t)b * BSLOT_DW,
                        h_ex + SLOT_DW + (size_t)b * BSLOT_DW };
  uint32_t* pub01[2] = { hrec[0] + 32 * g, hrec[1] + 32 * g };

  __syncthreads();

  int dead = 0;
  for (int t = 0; t < T_STEPS; ++t) {
    const int sl = t & 1, ns = sl ^ 1;

    // ---- wave 15: scalar poll, vL1-inv, vector fetch -> LDS ----
    if (wv == 15) {
      {
        int guard = 0;
        for (;;) {
          kinv();
          u32x8 tg = sload8(tagu);
          bool ok = ((int)tg[0] >= t) & ((int)tg[1] >= t) &
                    ((int)tg[2] >= t) & ((int)tg[3] >= t) &
                    ((int)tg[4] >= t) & ((int)tg[5] >= t) &
                    ((int)tg[6] >= t) & ((int)tg[7] >= t);
          if (ok) break;
          if (dead || ++guard > (1 << 16)) { dead = 1; break; }  // anti-hang
        }
      }
      // acquire-agent fence: lowers to s_waitcnt + buffer_inv (drop this
      // CU's vL1) on gfx950. NO sc1 on the data loads below -> L2-served.
      __builtin_amdgcn_fence(__ATOMIC_ACQUIRE, "agent");
      const u32x4* src = (const u32x4*)hrec[sl];
      u32x4 v = src[l];                       // 64 lanes x 16B = whole record
      *(u32x4*)&h_lds[sl][4 * l] = v;         // ds_write_b128
    }
    __syncthreads();   // barrier #1: h_lds[sl] ready

    // ---- matvec: 2 rows x 64 cols per lane; h via broadcast ds_read_b128 ----
    const u32x4* hs4 = (const u32x4*)&h_lds[sl][32 * cs];
    float acc0a = 0.f, acc0b = 0.f, acc1a = 0.f, acc1b = 0.f;
#pragma unroll
    for (int k = 0; k < 8; ++k) {
      u32x4 hv = hs4[k];
      acc0a = fdot2(w0[4 * k + 0], hv[0], acc0a);
      acc1a = fdot2(w1[4 * k + 0], hv[0], acc1a);
      acc0b = fdot2(w0[4 * k + 1], hv[1], acc0b);
      acc1b = fdot2(w1[4 * k + 1], hv[1], acc1b);
      acc0a = fdot2(w0[4 * k + 2], hv[2], acc0a);
      acc1a = fdot2(w1[4 * k + 2], hv[2], acc1a);
      acc0b = fdot2(w0[4 * k + 3], hv[3], acc0b);
      acc1b = fdot2(w1[4 * k + 3], hv[3], acc1b);
    }
    atomicAdd(&gacc[sl][128 * rg + l], acc0a + acc0b);      // conflict-free
    atomicAdd(&gacc[sl][128 * rg + 64 + l], acc1a + acc1b);
    __syncthreads();   // barrier #2: gacc complete

    // ---- activations + publish (wave 0, 64 lanes = 64 owned units) ----
    if (tid < 64) {
      const float xv = x0_lds[t];
      float gi = gacc[sl][tid]       + xv * wih_[0] + bs_[0];
      float gf = gacc[sl][tid + 64]  + xv * wih_[1] + bs_[1];
      float gg = gacc[sl][tid + 128] + xv * wih_[2] + bs_[2];
      float go = gacc[sl][tid + 192] + xv * wih_[3] + bs_[3];
      float si = sigf(gi), sf = sigf(gf), tg_ = tanh_fast(gg), so = sigf(go);
      c_state = sf * c_state + si * tg_;
      float h = so * tanh_fast(c_state);

      // publish: per-lane 2B store (no shfl on the critical path); layout
      // identical to packed f16x2 dwords. Write-through vL1 -> L2.
      ((_Float16*)pub01[ns])[tid] = (_Float16)h;
      // wave-level drain (data visible in L2), then the tag "release".
      asm volatile("s_waitcnt vmcnt(0)" ::: "memory");
      if (tid == 0) *(volatile uint32_t*)(tags_b + g) = (uint32_t)(t + 1);

      // recycle gacc[sl] for step t+2 (ordering via the barrier chain)
      gacc[sl][tid] = 0.f;
      gacc[sl][tid + 64] = 0.f;
      gacc[sl][tid + 128] = 0.f;
      gacc[sl][tid + 192] = 0.f;

      // y partial (off critical path): fold 64 units -> ylds[t]
      float p = wlin_u * h;
#pragma unroll
      for (int m = 32; m >= 1; m >>= 1) p += __shfl_xor(p, m, 64);
      if (tid == 0) ylds[t] = p;
    }
  }

  // ---- drain: block partials -> global y (g==0 adds bias + residual) ----
  __syncthreads();
  for (int i = tid; i < T_STEPS; i += BLK_THREADS) {
    float val = ylds[i];
    if (g == 0) val += blin + x0_lds[i];
    unsafeAtomicAdd(&y[i * BATCH + b], val);
  }
}

extern "C" void kernel_launch(void* const* d_in, const int* in_sizes, int n_in,
                              void* d_out, int out_size, void* d_ws, size_t ws_size,
                              hipStream_t stream) {
  const float* x0    = (const float*)d_in[0];
  const float* W_ih  = (const float*)d_in[1];
  const float* W_hh  = (const float*)d_in[2];
  const float* b_ih  = (const float*)d_in[3];
  const float* b_hh  = (const float*)d_in[4];
  const float* W_lin = (const float*)d_in[5];
  const float* b_lin = (const float*)d_in[6];
  float* y = (float*)d_out;

  uint32_t* h_ex = (uint32_t*)d_ws;                    // 2 x 32 KB slots
  uint32_t* tags = h_ex + 2 * SLOT_DW;                 // 1 KB
  int* claim     = (int*)(tags + BATCH * 8);           // 512 B
  const size_t init_bytes = (size_t)(2 * SLOT_DW + BATCH * 8) * sizeof(uint32_t)
                            + 8 * 16 * sizeof(int);

  // memset 0: slot-0 h = 0 (== h0), tags = 0 ("h_0 available"), claim = 0
  (void)hipMemsetAsync(d_ws, 0, init_bytes, stream);
  (void)hipMemsetAsync(d_out, 0, (size_t)out_size * sizeof(float), stream);

  hipLaunchKernelGGL(lstm_spoll, dim3(NBLOCKS), dim3(BLK_THREADS), 0, stream,
                     x0, W_ih, W_hh, b_ih, b_hh, W_lin, b_lin, y, h_ex, tags,
                     claim);
}